// Round 11
// baseline (801.838 us; speedup 1.0000x reference)
//
#include <hip/hip_runtime.h>

#define NV    50000
#define DCH   512
#define NEDGE 150000
#define MPAD  50176   // 392 * 128 = 196 * 256

typedef float  f32x4  __attribute__((ext_vector_type(4)));
typedef __bf16 bf16x8 __attribute__((ext_vector_type(8)));
typedef unsigned short us8 __attribute__((ext_vector_type(8)));

__device__ __forceinline__ unsigned short f2bf(float f) {
  unsigned int u = __builtin_bit_cast(unsigned int, f);
  u += 0x7fffu + ((u >> 16) & 1u);
  return (unsigned short)(u >> 16);
}

__device__ __forceinline__ float bf2f(unsigned short h) {
  return __builtin_bit_cast(float, (unsigned int)h << 16);
}

__device__ __forceinline__ void store_bf16x8(unsigned short* op, float4 a, float4 b) {
  us8 o;
  o[0] = f2bf(a.x); o[1] = f2bf(a.y); o[2] = f2bf(a.z); o[3] = f2bf(a.w);
  o[4] = f2bf(b.x); o[5] = f2bf(b.y); o[6] = f2bf(b.z); o[7] = f2bf(b.w);
  *(us8*)op = o;
}

__device__ __forceinline__ void unpack8(us8 v, float4& a, float4& b) {
  a.x = bf2f(v[0]); a.y = bf2f(v[1]); a.z = bf2f(v[2]); a.w = bf2f(v[3]);
  b.x = bf2f(v[4]); b.y = bf2f(v[5]); b.z = bf2f(v[6]); b.w = bf2f(v[7]);
}

// ---------------- structs ----------------
struct WtJob  { const float* w; unsigned short* dst; int ldk, koff; };
struct WtJobs { WtJob j[6]; };
struct CsrP  { const int* ei; int* counts; int* cursor; int* incl; int* off; int* csrc; int* bsum; };
struct Csr3  { CsrP c[3]; };

// ---------------- prep mega-kernel: wt (6 jobs) + cvt_x (2) + hist (3) ----------------
__global__ void prep_k(WtJobs wj, Csr3 cs,
                       const float* __restrict__ xa, const float* __restrict__ xb,
                       unsigned short* __restrict__ oa, unsigned short* __restrict__ ob) {
  int b = blockIdx.x, tid = threadIdx.x;
  if (b < 6144) {
    const WtJob J = wj.j[b >> 10];
    int idx = (b & 1023) * 256 + tid;        // 1024*256 == 512*512 exact
    int k = idx >> 9, n = idx & 511;
    J.dst[(size_t)n * J.ldk + J.koff + k] = f2bf(J.w[(size_t)k * 512 + n]);
  } else if (b < 31144) {
    int rel = b - 6144;
    const float* s = (rel < 12500) ? xa : xb;
    unsigned short* d = (rel < 12500) ? oa : ob;
    int i = (rel % 12500) * 256 + tid;       // 12500*256 == NV*DCH/8 exact
    const float* sp = s + (size_t)i * 8;
    f32x4 u = __builtin_nontemporal_load((const f32x4*)sp);
    f32x4 v = __builtin_nontemporal_load((const f32x4*)(sp + 4));
    us8 o;
    o[0] = f2bf(u[0]); o[1] = f2bf(u[1]); o[2] = f2bf(u[2]); o[3] = f2bf(u[3]);
    o[4] = f2bf(v[0]); o[5] = f2bf(v[1]); o[6] = f2bf(v[2]); o[7] = f2bf(v[3]);
    *(us8*)(d + (size_t)i * 8) = o;
  } else {
    int rel = b - 31144;
    const CsrP C = cs.c[rel / 587];
    int e = (rel % 587) * 256 + tid;
    if (e < NEDGE) atomicAdd(&C.counts[C.ei[NEDGE + e]], 1);
  }
}

// ---------------- CSR scans (z-batched over the 3 edge types) ----------------
__global__ void scan1(Csr3 cs) {
  const CsrP C = cs.c[blockIdx.z];
  __shared__ int sm[1024];
  int t = threadIdx.x, b = blockIdx.x;
  int i = b * 1024 + t;
  int v = (i < NV) ? C.counts[i] : 0;
  sm[t] = v; __syncthreads();
  for (int off = 1; off < 1024; off <<= 1) {
    int x = sm[t];
    int y = (t >= off) ? sm[t - off] : 0;
    __syncthreads();
    sm[t] = x + y;
    __syncthreads();
  }
  if (i < NV) C.incl[i] = sm[t];
  if (t == 1023) C.bsum[b] = sm[t];
}

// scan3': folds the 49-block prefix into each thread's local sum.
__global__ void scan3(Csr3 cs) {
  const CsrP C = cs.c[blockIdx.z];
  int i = blockIdx.x * 256 + threadIdx.x;
  if (i < NV) {
    int nb = i >> 10;
    int run = 0;
    for (int j = 0; j < nb; ++j) run += C.bsum[j];
    int v = C.incl[i] - C.counts[i] + run;
    C.off[i] = v;
    C.cursor[i] = v;
  } else if (i == NV) {
    C.off[NV] = NEDGE;
  }
}

__global__ void fill_csr(Csr3 cs) {
  const CsrP C = cs.c[blockIdx.z];
  int e = blockIdx.x * 256 + threadIdx.x;
  if (e >= NEDGE) return;
  int d = C.ei[NEDGE + e];
  int pos = atomicAdd(&C.cursor[d], 1);
  C.csrc[pos] = C.ei[e];
}

// ---------------- merged gather over bf16 sources ----------------
__device__ __forceinline__ void acc_rows16(const unsigned short* __restrict__ xsrc,
                                           const int* __restrict__ csrc,
                                           int s0, int s1, int lane,
                                           float4& a, float4& b) {
  int i = s0;
  for (; i + 1 < s1; i += 2) {
    us8 vA = *(const us8*)(xsrc + (size_t)csrc[i]     * DCH + lane * 8);
    us8 vB = *(const us8*)(xsrc + (size_t)csrc[i + 1] * DCH + lane * 8);
    float4 a0, b0, a1, b1;
    unpack8(vA, a0, b0);
    unpack8(vB, a1, b1);
    a.x += a0.x + a1.x; a.y += a0.y + a1.y; a.z += a0.z + a1.z; a.w += a0.w + a1.w;
    b.x += b0.x + b1.x; b.y += b0.y + b1.y; b.z += b0.z + b1.z; b.w += b0.w + b1.w;
  }
  if (i < s1) {
    us8 v = *(const us8*)(xsrc + (size_t)csrc[i] * DCH + lane * 8);
    float4 a0, b0;
    unpack8(v, a0, b0);
    a.x += a0.x; a.y += a0.y; a.z += a0.z; a.w += a0.w;
    b.x += b0.x; b.y += b0.y; b.z += b0.z; b.w += b0.w;
  }
}

__global__ void gather_all(const unsigned short* __restrict__ xa16,
                           const unsigned short* __restrict__ xb16,
                           const int* __restrict__ off_aa, const int* __restrict__ src_aa,
                           const int* __restrict__ off_ba, const int* __restrict__ src_ba,
                           const int* __restrict__ off_ab, const int* __restrict__ src_ab,
                           unsigned short* __restrict__ hb_aa,
                           unsigned short* __restrict__ hb_ba,
                           unsigned short* __restrict__ hb_ab) {
  int g = blockIdx.x * 256 + threadIdx.x;
  int node = g >> 6, lane = g & 63;
  if (node >= MPAD) return;
  size_t obase = (size_t)node * DCH + lane * 8;
  if (node >= NV) {
    us8 z = {0, 0, 0, 0, 0, 0, 0, 0};
    *(us8*)(hb_aa + obase) = z;
    *(us8*)(hb_ba + obase) = z;
    *(us8*)(hb_ab + obase) = z;
    return;
  }
  float4 da0, da1, db0, db1;
  unpack8(*(const us8*)(xa16 + obase), da0, da1);
  unpack8(*(const us8*)(xb16 + obase), db0, db1);
  float4 aa0 = da0, aa1 = da1;        // h_aa = x_a + sum(x_a srcs)
  float4 ba0 = da0, ba1 = da1;        // h_ba = x_a + sum(x_b srcs)
  float4 ab0 = db0, ab1 = db1;        // h_ab = x_b + sum(x_a srcs)

  acc_rows16(xa16, src_aa, off_aa[node], off_aa[node + 1], lane, aa0, aa1);
  acc_rows16(xb16, src_ba, off_ba[node], off_ba[node + 1], lane, ba0, ba1);
  acc_rows16(xa16, src_ab, off_ab[node], off_ab[node + 1], lane, ab0, ab1);

  store_bf16x8(hb_aa + obase, aa0, aa1);
  store_bf16x8(hb_ba + obase, ba0, ba1);
  store_bf16x8(hb_ab + obase, ab0, ab1);
}

// ---------------- GEMM: DIRECT-FROM-L2 fragments, zero K-loop barriers ----------------
// 128x128 tile, 4 waves (2x2), 16x16x32 bf16 MFMA. Both operands' fragments are
// loaded straight from global (L2/L3-resident: B panels 0.5-1MB; A streamed with
// 4x col-tile reuse). No LDS staging, no __syncthreads in the K-loop -> no vmcnt
// drain stall; compiler pipelines loads over MFMAs freely. k-mapping identical to
// the validated LDS kernel: frag = P[row][k0 + kk*32 + kq*8] (swizzle algebra cancels).
// LDS (32KB) used ONLY for the proven repack epilogue.
// Grid MUST be (4, 392, z): nwg=1568=8*196 -> exact XCD-chunked swizzle.
struct GemmJob  { const unsigned short* A; int lda; const unsigned short* Bt; int ldb;
                  const float* bias_a; const float* bias_b; void* out; int ldc; int col_off; };
struct GemmJobs { GemmJob j[3]; };

template<int MODE>
__global__ void gemm_tile(GemmJobs jobs) {
  const GemmJob J = jobs.j[blockIdx.z];
  __shared__ __align__(16) char smem[32768];
  const int t = threadIdx.x;
  const int wave = t >> 6, lane = t & 63;
  const int wr = wave >> 1, wc = wave & 1;

  // exact XCD-chunked swizzle (nwg = 1568 = 8 * 196)
  const int flat = blockIdx.x + (blockIdx.y << 2);
  const int wgid = (flat & 7) * 196 + (flat >> 3);
  const int row_base = (wgid >> 2) * 128;
  const int col_base = (wgid & 3) * 128;

  const int rl = lane & 15, kq = lane >> 4;

  f32x4 acc[4][4] = {};

  const int K = J.ldb;
  const int ktiles = K >> 6;
  const int lda = J.lda, ldb = J.ldb;

  // per-lane base pointers: A rows (wr*64 + m*16 + rl), B cols (wc*64 + n*16 + rl),
  // each at k-byte offset kq*16 within the 64B k-chunk.
  const unsigned short* Aptr[4];
  const unsigned short* Bptr[4];
#pragma unroll
  for (int m = 0; m < 4; ++m)
    Aptr[m] = J.A + (size_t)(row_base + wr * 64 + m * 16 + rl) * lda + kq * 8;
#pragma unroll
  for (int n = 0; n < 4; ++n)
    Bptr[n] = J.Bt + (size_t)(col_base + wc * 64 + n * 16 + rl) * ldb + kq * 8;

  for (int kt = 0; kt < ktiles; ++kt) {
    const int k0 = kt << 6;
#pragma unroll
    for (int kk = 0; kk < 2; ++kk) {
      bf16x8 af[4], bfr[4];
#pragma unroll
      for (int m = 0; m < 4; ++m)
        af[m] = *(const bf16x8*)(Aptr[m] + k0 + kk * 32);
#pragma unroll
      for (int n = 0; n < 4; ++n)
        bfr[n] = *(const bf16x8*)(Bptr[n] + k0 + kk * 32);
#pragma unroll
      for (int m = 0; m < 4; ++m)
#pragma unroll
        for (int n = 0; n < 4; ++n)
          acc[m][n] = __builtin_amdgcn_mfma_f32_16x16x32_bf16(af[m], bfr[n], acc[m][n], 0, 0, 0);
    }
  }

  // ---- epilogue: LDS repack -> coalesced stores ----
  float bb[4];
#pragma unroll
  for (int n = 0; n < 4; ++n) {
    int col = col_base + wc * 64 + n * 16 + rl;
    bb[n] = J.bias_a[col] + ((MODE == 1 && J.bias_b) ? J.bias_b[col] : 0.0f);
  }

  if (MODE == 0) {
    unsigned short* Ch = (unsigned short*)smem;   // [128][128] bf16 = 32 KB
#pragma unroll
    for (int m = 0; m < 4; ++m)
#pragma unroll
      for (int n = 0; n < 4; ++n) {
        int col = wc * 64 + n * 16 + rl;
#pragma unroll
        for (int j = 0; j < 4; ++j) {
          int row = wr * 64 + m * 16 + kq * 4 + j;
          float v = fmaxf(acc[m][n][j] + bb[n], 0.0f);
          Ch[row * 128 + col] = f2bf(v);
        }
      }
    __syncthreads();
    unsigned short* out = (unsigned short*)J.out;
#pragma unroll
    for (int i = 0; i < 8; ++i) {
      int f = i * 256 + t;            // us8 granules, 2048 total
      int rloc = f >> 4, c8 = f & 15;
      us8 v = *(const us8*)&Ch[rloc * 128 + c8 * 8];
      *(us8*)&out[(size_t)(row_base + rloc) * J.ldc + J.col_off + col_base + c8 * 8] = v;
    }
  } else {
    float* Cf = (float*)smem;                     // [64][128] f32 per round
    float* out = (float*)J.out;
#pragma unroll
    for (int p = 0; p < 2; ++p) {
      __syncthreads();
      if (wr == p) {
#pragma unroll
        for (int m = 0; m < 4; ++m)
#pragma unroll
          for (int n = 0; n < 4; ++n) {
            int col = wc * 64 + n * 16 + rl;
#pragma unroll
            for (int j = 0; j < 4; ++j) {
              int rloc = m * 16 + kq * 4 + j;
              Cf[rloc * 128 + col] = acc[m][n][j] + bb[n];
            }
          }
      }
      __syncthreads();
#pragma unroll
      for (int i = 0; i < 8; ++i) {
        int f = i * 256 + t;          // float4 granules, 2048 total
        int rloc = f >> 5, c4 = f & 31;
        int grow = row_base + p * 64 + rloc;
        if (grow < NV) {
          f32x4 v = *(const f32x4*)&Cf[rloc * 128 + c4 * 4];
          __builtin_nontemporal_store(v, (f32x4*)&out[(size_t)grow * J.ldc + col_base + c4 * 4]);
        }
      }
    }
  }
}

extern "C" void kernel_launch(void* const* d_in, const int* in_sizes, int n_in,
                              void* d_out, int out_size, void* d_ws, size_t ws_size,
                              hipStream_t stream) {
  const float* x_a  = (const float*)d_in[0];
  const float* x_b  = (const float*)d_in[1];
  const int* ei_aa  = (const int*)d_in[2];
  const int* ei_ab  = (const int*)d_in[3];
  const int* ei_ba  = (const int*)d_in[4];
  const float* w1_aa = (const float*)d_in[5];
  const float* b1_aa = (const float*)d_in[6];
  const float* w2_aa = (const float*)d_in[7];
  const float* b2_aa = (const float*)d_in[8];
  const float* w1_ab = (const float*)d_in[9];
  const float* b1_ab = (const float*)d_in[10];
  const float* w2_ab = (const float*)d_in[11];
  const float* b2_ab = (const float*)d_in[12];
  const float* w1_ba = (const float*)d_in[13];
  const float* b1_ba = (const float*)d_in[14];
  const float* w2_ba = (const float*)d_in[15];
  const float* b2_ba = (const float*)d_in[16];

  char* ws = (char*)d_ws;
  const size_t szH  = (size_t)MPAD * DCH * 2;          // bf16 [MPAD][512]
  const size_t szH2 = (size_t)MPAD * DCH * 2 * 2;      // bf16 [MPAD][1024]
  const size_t szX  = (size_t)NV * DCH * 2;            // bf16 [NV][512]
  size_t o = 0;
  unsigned short* hb_aa = (unsigned short*)(ws + o); o += szH;
  unsigned short* hb_ba = (unsigned short*)(ws + o); o += szH;
  unsigned short* hb_ab = (unsigned short*)(ws + o); o += szH;
  unsigned short* H1c   = (unsigned short*)(ws + o); o += szH2;  // [MPAD][1024]
  unsigned short* H1ab  = (unsigned short*)(ws + o); o += szH;
  unsigned short* xa16  = (unsigned short*)(ws + o); o += szX;
  unsigned short* xb16  = (unsigned short*)(ws + o); o += szX;
  unsigned short* w1t_aa = (unsigned short*)(ws + o); o += 512 * 512 * 2;
  unsigned short* w1t_ba = (unsigned short*)(ws + o); o += 512 * 512 * 2;
  unsigned short* w1t_ab = (unsigned short*)(ws + o); o += 512 * 512 * 2;
  unsigned short* w2tc   = (unsigned short*)(ws + o); o += 512 * 1024 * 2;
  unsigned short* w2t_ab = (unsigned short*)(ws + o); o += 512 * 512 * 2;

  int* counts3 = (int*)(ws + o); o += (size_t)3 * NV * 4;   // one memset

  Csr3 cs;
  const int* eis[3] = { ei_aa, ei_ab, ei_ba };
  for (int tI = 0; tI < 3; ++tI) {
    cs.c[tI].ei     = eis[tI];
    cs.c[tI].counts = counts3 + (size_t)tI * NV;
    cs.c[tI].cursor = (int*)(ws + o); o += (size_t)NV * 4;
    cs.c[tI].incl   = (int*)(ws + o); o += (size_t)NV * 4;
    cs.c[tI].off    = (int*)(ws + o); o += ((size_t)NV + 4) * 4;
    cs.c[tI].csrc   = (int*)(ws + o); o += (size_t)NEDGE * 4;
    cs.c[tI].bsum   = (int*)(ws + o); o += 64 * 4;
  }

  float* out_a = (float*)d_out;
  float* out_b = out_a + (size_t)NV * DCH;

  WtJobs wj;
  wj.j[0] = { w1_aa, w1t_aa, 512, 0 };
  wj.j[1] = { w1_ba, w1t_ba, 512, 0 };
  wj.j[2] = { w1_ab, w1t_ab, 512, 0 };
  wj.j[3] = { w2_aa, w2tc, 1024, 0 };
  wj.j[4] = { w2_ba, w2tc, 1024, 512 };
  wj.j[5] = { w2_ab, w2t_ab, 512, 0 };

  // 1) zero histograms
  (void)hipMemsetAsync(counts3, 0, (size_t)3 * NV * 4, stream);
  // 2) prep: wt + cvt_x + hist in one launch (independent segments)
  prep_k<<<32905, 256, 0, stream>>>(wj, cs, x_a, x_b, xa16, xb16);
  // 3-5) CSR: scan1, scan3', fill
  scan1<<<dim3(49, 1, 3), 1024, 0, stream>>>(cs);
  scan3<<<dim3(196, 1, 3), 256, 0, stream>>>(cs);
  fill_csr<<<dim3(587, 1, 3), 256, 0, stream>>>(cs);
  // 6) merged gather (aa: a<-a, ba: a<-b, ab: b<-a); zero-fills pad rows
  gather_all<<<MPAD / 4, 256, 0, stream>>>(
      xa16, xb16,
      cs.c[0].off, cs.c[0].csrc,      // aa
      cs.c[2].off, cs.c[2].csrc,      // ba
      cs.c[1].off, cs.c[1].csrc,      // ab
      hb_aa, hb_ba, hb_ab);

  // 7) layer 1: 3 GEMMs in one launch (K=512)
  GemmJobs g1;
  g1.j[0] = { hb_aa, 512, w1t_aa, 512, b1_aa, nullptr, H1c,  1024, 0 };
  g1.j[1] = { hb_ba, 512, w1t_ba, 512, b1_ba, nullptr, H1c,  1024, 512 };
  g1.j[2] = { hb_ab, 512, w1t_ab, 512, b1_ab, nullptr, H1ab, 512,  0 };
  gemm_tile<0><<<dim3(4, 392, 3), 256, 0, stream>>>(g1);

  // 8) layer 2: merged-K GEMM (aa+ba, K=1024) and ab GEMM (K=512)
  GemmJobs g2;
  g2.j[0] = { H1c,  1024, w2tc,   1024, b2_aa, b2_ba,  out_a, 512, 0 };
  g2.j[1] = { H1ab, 512,  w2t_ab, 512,  b2_ab, nullptr, out_b, 512, 0 };
  g2.j[2] = g2.j[1];   // unused (grid z=2)
  gemm_tile<1><<<dim3(4, 392, 2), 256, 0, stream>>>(g2);
}

// Round 12
// 416.023 us; speedup vs baseline: 1.9274x; 1.9274x over previous
//
#include <hip/hip_runtime.h>

#define NV    50000
#define DCH   512
#define NEDGE 150000
#define MPAD  50176   // 392 * 128 = 196 * 256

typedef float  f32x4  __attribute__((ext_vector_type(4)));
typedef __bf16 bf16x8 __attribute__((ext_vector_type(8)));
typedef unsigned short us8 __attribute__((ext_vector_type(8)));

__device__ __forceinline__ unsigned short f2bf(float f) {
  unsigned int u = __builtin_bit_cast(unsigned int, f);
  u += 0x7fffu + ((u >> 16) & 1u);
  return (unsigned short)(u >> 16);
}

__device__ __forceinline__ float bf2f(unsigned short h) {
  return __builtin_bit_cast(float, (unsigned int)h << 16);
}

__device__ __forceinline__ void g2lds16(const void* g, void* l) {
  typedef const __attribute__((address_space(1))) unsigned int* gp_t;
  typedef __attribute__((address_space(3))) unsigned int* lp_t;
  __builtin_amdgcn_global_load_lds((gp_t)g, (lp_t)l, 16, 0, 0);
}

__device__ __forceinline__ void unpack8(us8 v, float4& a, float4& b) {
  a.x = bf2f(v[0]); a.y = bf2f(v[1]); a.z = bf2f(v[2]); a.w = bf2f(v[3]);
  b.x = bf2f(v[4]); b.y = bf2f(v[5]); b.z = bf2f(v[6]); b.w = bf2f(v[7]);
}

// ---------------- structs ----------------
struct WtJob  { const float* w; unsigned short* dst; int ldk, koff; };
struct WtJobs { WtJob j[6]; };
struct CsrP  { const int* ei; int* counts; int* cursor; int* incl; int* off; int* csrc; int* bsum; };
struct Csr3  { CsrP c[3]; };

// ---------------- prep mega-kernel: wt (6 jobs) + cvt_x (2) + hist (3) ----------------
__global__ void prep_k(WtJobs wj, Csr3 cs,
                       const float* __restrict__ xa, const float* __restrict__ xb,
                       unsigned short* __restrict__ oa, unsigned short* __restrict__ ob) {
  int b = blockIdx.x, tid = threadIdx.x;
  if (b < 6144) {
    const WtJob J = wj.j[b >> 10];
    int idx = (b & 1023) * 256 + tid;        // 1024*256 == 512*512 exact
    int k = idx >> 9, n = idx & 511;
    J.dst[(size_t)n * J.ldk + J.koff + k] = f2bf(J.w[(size_t)k * 512 + n]);
  } else if (b < 31144) {
    int rel = b - 6144;
    const float* s = (rel < 12500) ? xa : xb;
    unsigned short* d = (rel < 12500) ? oa : ob;
    int i = (rel % 12500) * 256 + tid;       // 12500*256 == NV*DCH/8 exact
    const float* sp = s + (size_t)i * 8;
    f32x4 u = __builtin_nontemporal_load((const f32x4*)sp);
    f32x4 v = __builtin_nontemporal_load((const f32x4*)(sp + 4));
    us8 o;
    o[0] = f2bf(u[0]); o[1] = f2bf(u[1]); o[2] = f2bf(u[2]); o[3] = f2bf(u[3]);
    o[4] = f2bf(v[0]); o[5] = f2bf(v[1]); o[6] = f2bf(v[2]); o[7] = f2bf(v[3]);
    *(us8*)(d + (size_t)i * 8) = o;
  } else {
    int rel = b - 31144;
    const CsrP C = cs.c[rel / 587];
    int e = (rel % 587) * 256 + tid;
    if (e < NEDGE) atomicAdd(&C.counts[C.ei[NEDGE + e]], 1);
  }
}

// ---------------- CSR scans (z-batched over the 3 edge types) ----------------
__global__ void scan1(Csr3 cs) {
  const CsrP C = cs.c[blockIdx.z];
  __shared__ int sm[1024];
  int t = threadIdx.x, b = blockIdx.x;
  int i = b * 1024 + t;
  int v = (i < NV) ? C.counts[i] : 0;
  sm[t] = v; __syncthreads();
  for (int off = 1; off < 1024; off <<= 1) {
    int x = sm[t];
    int y = (t >= off) ? sm[t - off] : 0;
    __syncthreads();
    sm[t] = x + y;
    __syncthreads();
  }
  if (i < NV) C.incl[i] = sm[t];
  if (t == 1023) C.bsum[b] = sm[t];
}

// scan3': folds the 49-block prefix into each thread's local sum.
__global__ void scan3(Csr3 cs) {
  const CsrP C = cs.c[blockIdx.z];
  int i = blockIdx.x * 256 + threadIdx.x;
  if (i < NV) {
    int nb = i >> 10;
    int run = 0;
    for (int j = 0; j < nb; ++j) run += C.bsum[j];
    int v = C.incl[i] - C.counts[i] + run;
    C.off[i] = v;
    C.cursor[i] = v;
  } else if (i == NV) {
    C.off[NV] = NEDGE;
  }
}

__global__ void fill_csr(Csr3 cs) {
  const CsrP C = cs.c[blockIdx.z];
  int e = blockIdx.x * 256 + threadIdx.x;
  if (e >= NEDGE) return;
  int d = C.ei[NEDGE + e];
  int pos = atomicAdd(&C.cursor[d], 1);
  C.csrc[pos] = C.ei[e];
}

// ---------------- gather, split per (node, edge-type): z in {0:aa, 1:ba, 2:ab} ----
// 3x the waves of the merged version, ~3-iteration loops each -> better latency
// hiding; dst re-reads are L3-resident bf16 (51 MB/matrix). One wave per node.
struct GatherJob { const unsigned short* xdst; const unsigned short* xsrc;
                   const int* off; const int* csrc; unsigned short* hb; };
struct GatherJobs { GatherJob j[3]; };

__global__ void gather3(GatherJobs gj) {
  const GatherJob G = gj.j[blockIdx.z];
  int g = blockIdx.x * 256 + threadIdx.x;
  int node = g >> 6, lane = g & 63;
  size_t obase = (size_t)node * DCH + lane * 8;
  if (node >= NV) {
    us8 z = {0, 0, 0, 0, 0, 0, 0, 0};
    *(us8*)(G.hb + obase) = z;
    return;
  }
  float4 a, b;
  unpack8(*(const us8*)(G.xdst + obase), a, b);
  int i = G.off[node], s1 = G.off[node + 1];
  for (; i + 1 < s1; i += 2) {
    us8 vA = *(const us8*)(G.xsrc + (size_t)G.csrc[i]     * DCH + lane * 8);
    us8 vB = *(const us8*)(G.xsrc + (size_t)G.csrc[i + 1] * DCH + lane * 8);
    float4 a0, b0, a1, b1;
    unpack8(vA, a0, b0);
    unpack8(vB, a1, b1);
    a.x += a0.x + a1.x; a.y += a0.y + a1.y; a.z += a0.z + a1.z; a.w += a0.w + a1.w;
    b.x += b0.x + b1.x; b.y += b0.y + b1.y; b.z += b0.z + b1.z; b.w += b0.w + b1.w;
  }
  if (i < s1) {
    us8 v = *(const us8*)(G.xsrc + (size_t)G.csrc[i] * DCH + lane * 8);
    float4 a0, b0;
    unpack8(v, a0, b0);
    a.x += a0.x; a.y += a0.y; a.z += a0.z; a.w += a0.w;
    b.x += b0.x; b.y += b0.y; b.z += b0.z; b.w += b0.w;
  }
  us8 o;
  o[0] = f2bf(a.x); o[1] = f2bf(a.y); o[2] = f2bf(a.z); o[3] = f2bf(a.w);
  o[4] = f2bf(b.x); o[5] = f2bf(b.y); o[6] = f2bf(b.z); o[7] = f2bf(b.w);
  *(us8*)(G.hb + obase) = o;
}

// ---------------- GEMM (r10, measured best: 124/121 us), z-batched ----------------
// 128x128 tile, BK=64, 4 waves (2x2), 16x16x32 bf16 MFMA; single-buffer K-loop
// (dbuf/1-barrier regressed r6; 8-phase null at K<=1024 r8; direct-L2 regressed r11 —
// LDS staging IS the request-coalescing mechanism, do not remove).
// LDS-repack coalesced epilogue. Grid MUST be (4, 392, z): nwg=1568=8*196 swizzle.
struct GemmJob  { const unsigned short* A; int lda; const unsigned short* Bt; int ldb;
                  const float* bias_a; const float* bias_b; void* out; int ldc; int col_off; };
struct GemmJobs { GemmJob j[3]; };

template<int MODE>
__global__ void gemm_tile(GemmJobs jobs) {
  const GemmJob J = jobs.j[blockIdx.z];
  __shared__ __align__(16) char smem[32768];
  unsigned short* As = (unsigned short*)smem;             // [128*64] bf16, 16 KB
  unsigned short* Bs = (unsigned short*)(smem + 16384);   // [128*64] bf16, 16 KB
  const int t = threadIdx.x;
  const int wave = t >> 6, lane = t & 63;
  const int wr = wave >> 1, wc = wave & 1;

  // exact XCD-chunked swizzle (nwg = 1568 = 8 * 196)
  const int flat = blockIdx.x + (blockIdx.y << 2);
  const int wgid = (flat & 7) * 196 + (flat >> 3);
  const int row_base = (wgid >> 2) * 128;
  const int col_base = (wgid & 3) * 128;

  const int rl = lane & 15, kq = lane >> 4;

  f32x4 acc[4][4] = {};

  const int K = J.ldb;
  const int ktiles = K >> 6;
  const unsigned short* Ap = J.A;
  const unsigned short* Bp = J.Bt;
  const int lda = J.lda, ldb = J.ldb;
  for (int kt = 0; kt < ktiles; ++kt) {
    const int k0 = kt << 6;
#pragma unroll
    for (int i = 0; i < 4; ++i) {
      int q = i * 256 + t;
      int r = q >> 3, c = q & 7;
      int cg = c ^ (r & 7);   // pre-swizzled global source -> linear LDS dest
      g2lds16(Ap + (size_t)(row_base + r) * lda + k0 + cg * 8,
              &As[(size_t)(i * 256 + wave * 64) * 8]);
      g2lds16(Bp + (size_t)(col_base + r) * ldb + k0 + cg * 8,
              &Bs[(size_t)(i * 256 + wave * 64) * 8]);
    }
    __syncthreads();
#pragma unroll
    for (int kk = 0; kk < 2; ++kk) {
      bf16x8 af[4], bfr[4];
#pragma unroll
      for (int m = 0; m < 4; ++m) {
        int row = wr * 64 + m * 16 + rl;
        int cc = (kk * 4 + kq) ^ (row & 7);
        af[m] = *(const bf16x8*)&As[(row * 8 + cc) * 8];
      }
#pragma unroll
      for (int n = 0; n < 4; ++n) {
        int col = wc * 64 + n * 16 + rl;
        int cc = (kk * 4 + kq) ^ (col & 7);
        bfr[n] = *(const bf16x8*)&Bs[(col * 8 + cc) * 8];
      }
#pragma unroll
      for (int m = 0; m < 4; ++m)
#pragma unroll
        for (int n = 0; n < 4; ++n)
          acc[m][n] = __builtin_amdgcn_mfma_f32_16x16x32_bf16(af[m], bfr[n], acc[m][n], 0, 0, 0);
    }
    __syncthreads();
  }

  // ---- epilogue: LDS repack -> coalesced stores ----
  float bb[4];
#pragma unroll
  for (int n = 0; n < 4; ++n) {
    int col = col_base + wc * 64 + n * 16 + rl;
    bb[n] = J.bias_a[col] + ((MODE == 1 && J.bias_b) ? J.bias_b[col] : 0.0f);
  }

  if (MODE == 0) {
    unsigned short* Ch = (unsigned short*)smem;   // [128][128] bf16 = 32 KB
#pragma unroll
    for (int m = 0; m < 4; ++m)
#pragma unroll
      for (int n = 0; n < 4; ++n) {
        int col = wc * 64 + n * 16 + rl;
#pragma unroll
        for (int j = 0; j < 4; ++j) {
          int row = wr * 64 + m * 16 + kq * 4 + j;
          float v = fmaxf(acc[m][n][j] + bb[n], 0.0f);
          Ch[row * 128 + col] = f2bf(v);
        }
      }
    __syncthreads();
    unsigned short* out = (unsigned short*)J.out;
#pragma unroll
    for (int i = 0; i < 8; ++i) {
      int f = i * 256 + t;            // us8 granules, 2048 total
      int rloc = f >> 4, c8 = f & 15;
      us8 v = *(const us8*)&Ch[rloc * 128 + c8 * 8];
      *(us8*)&out[(size_t)(row_base + rloc) * J.ldc + J.col_off + col_base + c8 * 8] = v;
    }
  } else {
    float* Cf = (float*)smem;                     // [64][128] f32 per round
    float* out = (float*)J.out;
#pragma unroll
    for (int p = 0; p < 2; ++p) {
      __syncthreads();
      if (wr == p) {
#pragma unroll
        for (int m = 0; m < 4; ++m)
#pragma unroll
          for (int n = 0; n < 4; ++n) {
            int col = wc * 64 + n * 16 + rl;
#pragma unroll
            for (int j = 0; j < 4; ++j) {
              int rloc = m * 16 + kq * 4 + j;
              Cf[rloc * 128 + col] = acc[m][n][j] + bb[n];
            }
          }
      }
      __syncthreads();
#pragma unroll
      for (int i = 0; i < 8; ++i) {
        int f = i * 256 + t;          // float4 granules, 2048 total
        int rloc = f >> 5, c4 = f & 31;
        int grow = row_base + p * 64 + rloc;
        if (grow < NV) {
          f32x4 v = *(const f32x4*)&Cf[rloc * 128 + c4 * 4];
          __builtin_nontemporal_store(v, (f32x4*)&out[(size_t)grow * J.ldc + col_base + c4 * 4]);
        }
      }
    }
  }
}

extern "C" void kernel_launch(void* const* d_in, const int* in_sizes, int n_in,
                              void* d_out, int out_size, void* d_ws, size_t ws_size,
                              hipStream_t stream) {
  const float* x_a  = (const float*)d_in[0];
  const float* x_b  = (const float*)d_in[1];
  const int* ei_aa  = (const int*)d_in[2];
  const int* ei_ab  = (const int*)d_in[3];
  const int* ei_ba  = (const int*)d_in[4];
  const float* w1_aa = (const float*)d_in[5];
  const float* b1_aa = (const float*)d_in[6];
  const float* w2_aa = (const float*)d_in[7];
  const float* b2_aa = (const float*)d_in[8];
  const float* w1_ab = (const float*)d_in[9];
  const float* b1_ab = (const float*)d_in[10];
  const float* w2_ab = (const float*)d_in[11];
  const float* b2_ab = (const float*)d_in[12];
  const float* w1_ba = (const float*)d_in[13];
  const float* b1_ba = (const float*)d_in[14];
  const float* w2_ba = (const float*)d_in[15];
  const float* b2_ba = (const float*)d_in[16];

  char* ws = (char*)d_ws;
  const size_t szH  = (size_t)MPAD * DCH * 2;          // bf16 [MPAD][512]
  const size_t szH2 = (size_t)MPAD * DCH * 2 * 2;      // bf16 [MPAD][1024]
  const size_t szX  = (size_t)NV * DCH * 2;            // bf16 [NV][512]
  size_t o = 0;
  unsigned short* hb_aa = (unsigned short*)(ws + o); o += szH;
  unsigned short* hb_ba = (unsigned short*)(ws + o); o += szH;
  unsigned short* hb_ab = (unsigned short*)(ws + o); o += szH;
  unsigned short* H1c   = (unsigned short*)(ws + o); o += szH2;  // [MPAD][1024]
  unsigned short* H1ab  = (unsigned short*)(ws + o); o += szH;
  unsigned short* xa16  = (unsigned short*)(ws + o); o += szX;
  unsigned short* xb16  = (unsigned short*)(ws + o); o += szX;
  unsigned short* w1t_aa = (unsigned short*)(ws + o); o += 512 * 512 * 2;
  unsigned short* w1t_ba = (unsigned short*)(ws + o); o += 512 * 512 * 2;
  unsigned short* w1t_ab = (unsigned short*)(ws + o); o += 512 * 512 * 2;
  unsigned short* w2tc   = (unsigned short*)(ws + o); o += 512 * 1024 * 2;
  unsigned short* w2t_ab = (unsigned short*)(ws + o); o += 512 * 512 * 2;

  int* counts3 = (int*)(ws + o); o += (size_t)3 * NV * 4;   // one memset

  Csr3 cs;
  const int* eis[3] = { ei_aa, ei_ab, ei_ba };
  for (int tI = 0; tI < 3; ++tI) {
    cs.c[tI].ei     = eis[tI];
    cs.c[tI].counts = counts3 + (size_t)tI * NV;
    cs.c[tI].cursor = (int*)(ws + o); o += (size_t)NV * 4;
    cs.c[tI].incl   = (int*)(ws + o); o += (size_t)NV * 4;
    cs.c[tI].off    = (int*)(ws + o); o += ((size_t)NV + 4) * 4;
    cs.c[tI].csrc   = (int*)(ws + o); o += (size_t)NEDGE * 4;
    cs.c[tI].bsum   = (int*)(ws + o); o += 64 * 4;
  }

  float* out_a = (float*)d_out;
  float* out_b = out_a + (size_t)NV * DCH;

  WtJobs wj;
  wj.j[0] = { w1_aa, w1t_aa, 512, 0 };
  wj.j[1] = { w1_ba, w1t_ba, 512, 0 };
  wj.j[2] = { w1_ab, w1t_ab, 512, 0 };
  wj.j[3] = { w2_aa, w2tc, 1024, 0 };
  wj.j[4] = { w2_ba, w2tc, 1024, 512 };
  wj.j[5] = { w2_ab, w2t_ab, 512, 0 };

  // 1) zero histograms
  (void)hipMemsetAsync(counts3, 0, (size_t)3 * NV * 4, stream);
  // 2) prep: wt + cvt_x + hist in one launch (independent segments)
  prep_k<<<32905, 256, 0, stream>>>(wj, cs, x_a, x_b, xa16, xb16);
  // 3-5) CSR: scan1, scan3', fill
  scan1<<<dim3(49, 1, 3), 1024, 0, stream>>>(cs);
  scan3<<<dim3(196, 1, 3), 256, 0, stream>>>(cs);
  fill_csr<<<dim3(587, 1, 3), 256, 0, stream>>>(cs);
  // 6) gather, one wave per (node, type): z=0 aa (a<-a), z=1 ba (a<-b), z=2 ab (b<-a)
  GatherJobs gj;
  gj.j[0] = { xa16, xa16, cs.c[0].off, cs.c[0].csrc, hb_aa };
  gj.j[1] = { xa16, xb16, cs.c[2].off, cs.c[2].csrc, hb_ba };
  gj.j[2] = { xb16, xa16, cs.c[1].off, cs.c[1].csrc, hb_ab };
  gather3<<<dim3(MPAD / 4, 1, 3), 256, 0, stream>>>(gj);

  // 7) layer 1: 3 GEMMs in one launch (K=512)
  GemmJobs g1;
  g1.j[0] = { hb_aa, 512, w1t_aa, 512, b1_aa, nullptr, H1c,  1024, 0 };
  g1.j[1] = { hb_ba, 512, w1t_ba, 512, b1_ba, nullptr, H1c,  1024, 512 };
  g1.j[2] = { hb_ab, 512, w1t_ab, 512, b1_ab, nullptr, H1ab, 512,  0 };
  gemm_tile<0><<<dim3(4, 392, 3), 256, 0, stream>>>(g1);

  // 8) layer 2: merged-K GEMM (aa+ba, K=1024) and ab GEMM (K=512)
  GemmJobs g2;
  g2.j[0] = { H1c,  1024, w2tc,   1024, b2_aa, b2_ba,  out_a, 512, 0 };
  g2.j[1] = { H1ab, 512,  w2t_ab, 512,  b2_ab, nullptr, out_b, 512, 0 };
  g2.j[2] = g2.j[1];   // unused (grid z=2)
  gemm_tile<1><<<dim3(4, 392, 2), 256, 0, stream>>>(g2);
}